// Round 4
// baseline (168.430 us; speedup 1.0000x reference)
//
#include <hip/hip_runtime.h>
#include <hip/hip_fp16.h>

// Problem constants
#define NV   20000
#define KK   3
#define INF  150
#define HH   64
#define OO   128
#define PT   80
#define KTOT 5120      // 80 bins * 64 h
#define NB   160       // vertices per geo block (125 tiles x 4 ks = 500 blocks)
#define RS   72        // pch v-row stride, halves (64 + 8 pad)
#define CB   (NB * RS) // 11520 halves = 23040 B per buffer
#define XS   168       // x/W1 LDS col stride, halves (prep kernel)
#define NBIN 20        // bins per K-slice
#define NCH  10        // bins per conn chunk (LDS holds one chunk at a time)

typedef _Float16 fh8 __attribute__((ext_vector_type(8)));   // MFMA A/B frag (4 VGPRs)
typedef __attribute__((ext_vector_type(4))) float f32x4;    // MFMA C/D frag
typedef __attribute__((ext_vector_type(8))) unsigned short u16x8;

__device__ __forceinline__ unsigned short f2h(float f) {
    return __half_as_ushort(__float2half(f));
}
__device__ __forceinline__ float h2f(unsigned short u) {
    return __half2float(__ushort_as_half(u));
}
__device__ __forceinline__ _Float16 u2h(unsigned short u) {
    union { unsigned short s; _Float16 h; } c; c.s = u; return c.h;
}

// ---------------------------------------------------------------------------
// Fused prep kernel (unchanged).
// Blocks 0..127: transpose Wg[o] -> W2 [S][o][kk] fp16 via LDS.
// Blocks 128..752: h = relu(x @ W1^T) -> fp16, 32 rows/block via MFMA.
// ---------------------------------------------------------------------------
__global__ __launch_bounds__(256) void prep_kernel(
    const float* __restrict__ Wg, const float* __restrict__ x,
    const float* __restrict__ W1, unsigned short* __restrict__ W2,
    unsigned short* __restrict__ hb) {
    __shared__ __align__(16) unsigned char smem[32256];
    const int tid = threadIdx.x;

    if (blockIdx.x < 128) {
        float* lds = (float*)smem;                 // 64*81 words
        const int o = blockIdx.x;
        const float* src = Wg + o * KTOT;
        for (int t = tid; t < KTOT; t += 256) {    // t = h*80 + bin
            int h = t / 80, bin = t - h * 80;
            lds[h * 81 + bin] = src[t];
        }
        __syncthreads();
        for (int t = tid; t < KTOT; t += 256) {    // t = k = bin*64 + h
            W2[(t >> 5) * 4096 + o * 32 + (t & 31)] =
                f2h(lds[(t & 63) * 81 + (t >> 6)]);
        }
        return;
    }

    unsigned short* xs = (unsigned short*)smem;    // 32*168
    unsigned short* ws = xs + 32 * XS;             // 64*168
    const int n0 = (blockIdx.x - 128) * 32;

    for (int e = tid; e < 32 * INF; e += 256) {
        int r = e / INF, c = e - r * INF;
        xs[r * XS + c] = f2h(x[n0 * INF + e]);
    }
    for (int e = tid; e < 32 * 18; e += 256) {
        int r = e / 18, c = e - r * 18;
        xs[r * XS + 150 + c] = 0;
    }
    for (int e = tid; e < 64 * INF; e += 256) {
        int r = e / INF, c = e - r * INF;
        ws[r * XS + c] = f2h(W1[e]);
    }
    for (int e = tid; e < 64 * 18; e += 256) {
        int r = e / 18, c = e - r * 18;
        ws[r * XS + 150 + c] = 0;
    }
    __syncthreads();

    const int wv   = tid >> 6;
    const int lane = tid & 63;
    const int q    = lane >> 4;
    const int r16  = lane & 15;
    const int o0   = wv * 16;

    f32x4 acc0 = {0.f, 0.f, 0.f, 0.f};
    f32x4 acc1 = acc0;
    #pragma unroll
    for (int s = 0; s < 5; s++) {
        const int kb = s * 32 + q * 8;
        fh8 a0 = *(const fh8*)(xs + r16 * XS + kb);
        fh8 a1 = *(const fh8*)(xs + (16 + r16) * XS + kb);
        fh8 b  = *(const fh8*)(ws + (o0 + r16) * XS + kb);
        acc0 = __builtin_amdgcn_mfma_f32_16x16x32_f16(a0, b, acc0, 0, 0, 0);
        acc1 = __builtin_amdgcn_mfma_f32_16x16x32_f16(a1, b, acc1, 0, 0, 0);
    }
    #pragma unroll
    for (int r = 0; r < 4; r++) {
        float v0 = acc0[r] > 0.f ? acc0[r] : 0.f;
        float v1 = acc1[r] > 0.f ? acc1[r] : 0.f;
        hb[(n0 + q * 4 + r) * HH + o0 + r16]      = f2h(v0);
        hb[(n0 + 16 + q * 4 + r) * HH + o0 + r16] = f2h(v1);
    }
}

// ---------------------------------------------------------------------------
// Geo kernel v15: 2m x 4o wave grid -- halves the LDS A-read traffic.
// R3 post-mortem: v14 single-round grid worked (80.5->63us, predicted
// 50-60). Residual limiter per CU-bin (7.2K cyc): LDS pipe ~71% busy --
// A-frag ds_read_b128 = 20/wave x 8 waves = 160 instrs/block-bin because
// the pure o-split makes all 8 waves re-read the ENTIRE A-tile (8x dup).
// v15: wave (wm,wo) = (tid>>8, (tid>>6)&3) owns 5 m-frags x 2 o-frags.
// Each A-read now feeds 2 MFMA; A-dup 8->4; A-reads 160->80/block-bin.
// Cost: W2 B-frags duplicated 2x in TCP (L1-hit, cheap). MFMA count,
// gathers, cwr, barriers, LDS footprint, stores: unchanged.
// Deterministic partials: ks=0 -> fp32 d_out, ks>=1 -> fp16 parts[ks-1].
// ---------------------------------------------------------------------------
__global__ __launch_bounds__(512, 4) void geo_kernel(
    const int*   __restrict__ conn_idx, const float* __restrict__ conn_w,
    const unsigned short* __restrict__ W2, const unsigned short* __restrict__ hb,
    float* __restrict__ out, unsigned short* __restrict__ parts) {
    __shared__ __align__(16) unsigned short pch[2 * CB];       // 46080 B
    __shared__ __align__(16) unsigned short cp[NB * NCH * 8];  // 25600 B packed conn

    const int tid  = threadIdx.x;
    const int ks   = blockIdx.x & 3;             // K-slice 0..3
    const int n0   = (blockIdx.x >> 2) * NB;     // 0..124 * 160
    const int wm   = tid >> 8;                   // m-wave 0..1 (5 m-frags each)
    const int wo   = (tid >> 6) & 3;             // o-wave 0..3 (2 o-frags each)
    const int lane = tid & 63;
    const int q    = lane >> 4;
    const int r16  = lane & 15;
    const int j8   = tid & 7;                    // 16B segment of h row
    const int v0   = tid >> 3;                   // vertex 0..63 (also +64, +128)
    const bool lo  = (tid < 256);                // waves 0..3 own rows 128..159
    const int bbase = ks * NBIN;
    const int Sbase = ks * 40;                   // first 32-k step

    // Chunk 0 conn -> LDS, packed: cp[(v*NCH+cc)*8] = [i0,i1,i2,w0,w1,w2,0,0]
    for (int e = tid; e < NB * NCH; e += 512) {
        const int v = e / NCH, cc = e - v * NCH;
        const int g = (n0 + v) * (PT * KK) + (bbase + cc) * KK;
        u16x8 pk;
        pk[0] = (unsigned short)conn_idx[g];
        pk[1] = (unsigned short)conn_idx[g + 1];
        pk[2] = (unsigned short)conn_idx[g + 2];
        pk[3] = f2h(conn_w[g]);
        pk[4] = f2h(conn_w[g + 1]);
        pk[5] = f2h(conn_w[g + 2]);
        pk[6] = 0; pk[7] = 0;
        *(u16x8*)(cp + e * 8) = pk;
    }

    // Chunk 1 conn -> registers now (global latency amortized over bins 0..8),
    // drained to LDS at bin NCH-1. 1600 entries / 512 thr = 3 full + tid<64.
    u16x8 cpre0, cpre1, cpre2, cpre3 = {0, 0, 0, 0, 0, 0, 0, 0};
    {
        auto packc = [&](int e) {
            const int v = e / NCH, cc = e - v * NCH;
            const int g = (n0 + v) * (PT * KK) + (bbase + NCH + cc) * KK;
            u16x8 pk;
            pk[0] = (unsigned short)conn_idx[g];
            pk[1] = (unsigned short)conn_idx[g + 1];
            pk[2] = (unsigned short)conn_idx[g + 2];
            pk[3] = f2h(conn_w[g]);
            pk[4] = f2h(conn_w[g + 1]);
            pk[5] = f2h(conn_w[g + 2]);
            pk[6] = 0; pk[7] = 0;
            return pk;
        };
        cpre0 = packc(tid);
        cpre1 = packc(tid + 512);
        cpre2 = packc(tid + 1024);
        if (tid < NB * NCH - 1536) cpre3 = packc(tid + 1536);
    }

    f32x4 acc[5][2];
    #pragma unroll
    for (int m = 0; m < 5; m++) {
        acc[m][0] = (f32x4){0.f, 0.f, 0.f, 0.f};
        acc[m][1] = (f32x4){0.f, 0.f, 0.f, 0.f};
    }

    u16x8 pa, pb, pc;    // packed conn for rows v0, v0+64, v0+128
    fh8   hva0, hva1, hva2, hvb0, hvb1, hvb2, hvc0, hvc1, hvc2;

    auto loadg = [&](int cc) {                   // conn b128 + 6..9 gathers
        const int bb = (cc >= NCH) ? cc - NCH : cc;
        pa = *(const u16x8*)(cp + (v0 * NCH + bb) * 8);
        pb = *(const u16x8*)(cp + ((v0 + 64) * NCH + bb) * 8);
        hva0 = *(const fh8*)(hb + (int)pa[0] * HH + j8 * 8);
        hva1 = *(const fh8*)(hb + (int)pa[1] * HH + j8 * 8);
        hva2 = *(const fh8*)(hb + (int)pa[2] * HH + j8 * 8);
        hvb0 = *(const fh8*)(hb + (int)pb[0] * HH + j8 * 8);
        hvb1 = *(const fh8*)(hb + (int)pb[1] * HH + j8 * 8);
        hvb2 = *(const fh8*)(hb + (int)pb[2] * HH + j8 * 8);
        if (lo) {                                // wave-uniform (waves 0..3)
            pc = *(const u16x8*)(cp + ((v0 + 128) * NCH + bb) * 8);
            hvc0 = *(const fh8*)(hb + (int)pc[0] * HH + j8 * 8);
            hvc1 = *(const fh8*)(hb + (int)pc[1] * HH + j8 * 8);
            hvc2 = *(const fh8*)(hb + (int)pc[2] * HH + j8 * 8);
        }
    };
    auto cwr = [&](unsigned short* buf) {        // combine + 2..3 LDS b128 writes
        const _Float16 a0 = u2h(pa[3]), a1 = u2h(pa[4]), a2 = u2h(pa[5]);
        const _Float16 b0 = u2h(pb[3]), b1 = u2h(pb[4]), b2 = u2h(pb[5]);
        const fh8 A0 = {a0, a0, a0, a0, a0, a0, a0, a0};
        const fh8 A1 = {a1, a1, a1, a1, a1, a1, a1, a1};
        const fh8 A2 = {a2, a2, a2, a2, a2, a2, a2, a2};
        const fh8 B0 = {b0, b0, b0, b0, b0, b0, b0, b0};
        const fh8 B1 = {b1, b1, b1, b1, b1, b1, b1, b1};
        const fh8 B2 = {b2, b2, b2, b2, b2, b2, b2, b2};
        fh8 ra = hva0 * A0 + hva1 * A1 + hva2 * A2;
        fh8 rb = hvb0 * B0 + hvb1 * B1 + hvb2 * B2;
        *(fh8*)(buf + v0 * RS + j8 * 8)        = ra;
        *(fh8*)(buf + (v0 + 64) * RS + j8 * 8) = rb;
        if (lo) {
            const _Float16 c0 = u2h(pc[3]), c1 = u2h(pc[4]), c2 = u2h(pc[5]);
            const fh8 C0 = {c0, c0, c0, c0, c0, c0, c0, c0};
            const fh8 C1 = {c1, c1, c1, c1, c1, c1, c1, c1};
            const fh8 C2 = {c2, c2, c2, c2, c2, c2, c2, c2};
            fh8 rc = hvc0 * C0 + hvc1 * C1 + hvc2 * C2;
            *(fh8*)(buf + (v0 + 128) * RS + j8 * 8) = rc;
        }
    };
    auto mfmaph = [&](const unsigned short* buf, int cc) {   // 20 MFMA/wave
        const unsigned short* wp =
            W2 + (Sbase + cc * 2) * 4096 + r16 * 32 + q * 8;
        // 4 B-frags: (s, oo) for this wave's 2 o-frags. L1/L2-resident.
        const fh8 b00 = *(const fh8*)(wp + (wo * 2 + 0) * 512);
        const fh8 b01 = *(const fh8*)(wp + (wo * 2 + 1) * 512);
        const fh8 b10 = *(const fh8*)(wp + 4096 + (wo * 2 + 0) * 512);
        const fh8 b11 = *(const fh8*)(wp + 4096 + (wo * 2 + 1) * 512);
        #pragma unroll
        for (int s = 0; s < 2; s++) {
            const int ao = s * 32 + q * 8;
            const fh8 bf0 = s ? b10 : b00;
            const fh8 bf1 = s ? b11 : b01;
            #pragma unroll
            for (int m = 0; m < 5; m++) {
                fh8 af = *(const fh8*)(buf + ((wm * 5 + m) * 16 + r16) * RS + ao);
                acc[m][0] = __builtin_amdgcn_mfma_f32_16x16x32_f16(af, bf0, acc[m][0], 0, 0, 0);
                acc[m][1] = __builtin_amdgcn_mfma_f32_16x16x32_f16(af, bf1, acc[m][1], 0, 0, 0);
            }
        }
    };

    __syncthreads();                             // cp chunk0 visible

    // Prologue: bin 0 staged into buffer 0
    loadg(0);
    cwr(pch);
    __syncthreads();

    #pragma unroll 1
    for (int cc = 0; cc < NBIN; cc++) {
        if (cc == NCH - 1) {
            // Drain chunk1 regs -> cp. Prior barrier (end of bin NCH-2)
            // guarantees every wave finished loadg(NCH-1) reads of chunk0.
            *(u16x8*)(cp + tid * 8)          = cpre0;
            *(u16x8*)(cp + (tid + 512) * 8)  = cpre1;
            *(u16x8*)(cp + (tid + 1024) * 8) = cpre2;
            if (tid < NB * NCH - 1536)
                *(u16x8*)(cp + (tid + 1536) * 8) = cpre3;
            __syncthreads();
        }
        if (cc + 1 < NBIN) loadg(cc + 1);        // gathers in flight over MFMA
        mfmaph(&pch[(cc & 1) * CB], cc);
        if (cc + 1 < NBIN) cwr(&pch[((cc + 1) & 1) * CB]);
        __syncthreads();
    }

    // Partial store. D layout: row = q*4+reg, col = r16. 125*160 = 20000
    // exactly -> no guards. One writer per element per stage.
    if (ks == 0) {
        #pragma unroll
        for (int m = 0; m < 5; m++) {
            const int rb = n0 + (wm * 5 + m) * 16 + q * 4;
            #pragma unroll
            for (int r = 0; r < 4; r++) {
                out[(rb + r) * OO + (wo * 2 + 0) * 16 + r16] = acc[m][0][r];
                out[(rb + r) * OO + (wo * 2 + 1) * 16 + r16] = acc[m][1][r];
            }
        }
    } else {
        unsigned short* pp = parts + (ks - 1) * (NV * OO);
        #pragma unroll
        for (int m = 0; m < 5; m++) {
            const int rb = n0 + (wm * 5 + m) * 16 + q * 4;
            #pragma unroll
            for (int r = 0; r < 4; r++) {
                pp[(rb + r) * OO + (wo * 2 + 0) * 16 + r16] = f2h(acc[m][0][r]);
                pp[(rb + r) * OO + (wo * 2 + 1) * 16 + r16] = f2h(acc[m][1][r]);
            }
        }
    }
}

// ---------------------------------------------------------------------------
// Epilogue: v = part0(out) + part1+part2+part3 + bg; out = v*rsqrt(sum v^2).
// 32 rows/block, 8 threads per row. Reads then fully overwrites d_out.
// ---------------------------------------------------------------------------
__global__ __launch_bounds__(256) void norm_kernel(
    float* __restrict__ out, const unsigned short* __restrict__ parts,
    const float* __restrict__ bg) {
    const int tid = threadIdx.x;
    const int n   = blockIdx.x * 32 + (tid >> 3);
    const int l   = tid & 7;
    float v[16];
    float s = 0.f;
    #pragma unroll
    for (int i = 0; i < 16; i++) {
        const int o = i * 8 + l;
        const int e = n * OO + o;
        v[i] = out[e] + h2f(parts[e]) + h2f(parts[NV * OO + e]) +
               h2f(parts[2 * NV * OO + e]) + bg[o];
        s += v[i] * v[i];
    }
    for (int off = 4; off; off >>= 1) s += __shfl_down(s, off, 8);
    const float r = rsqrtf(__shfl(s, 0, 8));
    #pragma unroll
    for (int i = 0; i < 16; i++)
        out[n * OO + i * 8 + l] = v[i] * r;
}

// ---------------------------------------------------------------------------
extern "C" void kernel_launch(void* const* d_in, const int* in_sizes, int n_in,
                              void* d_out, int out_size, void* d_ws, size_t ws_size,
                              hipStream_t stream) {
    const float* x        = (const float*)d_in[0];
    const int*   conn_idx = (const int*)  d_in[1];
    const float* conn_w   = (const float*)d_in[2];
    const float* W1       = (const float*)d_in[3];
    const float* Wg       = (const float*)d_in[4];
    const float* bg       = (const float*)d_in[5];
    float*       out      = (float*)d_out;

    unsigned short* W2    = (unsigned short*)d_ws;         // 655,360 fp16 (1.31 MB)
    unsigned short* hb    = W2 + OO * KTOT;                // 1,280,000 fp16 (2.56 MB)
    unsigned short* parts = hb + NV * HH;                  // 3 x 2,560,000 fp16 (15.4 MB)

    hipLaunchKernelGGL(prep_kernel, dim3(128 + NV / 32), dim3(256), 0, stream,
                       Wg, x, W1, W2, hb);
    hipLaunchKernelGGL(geo_kernel, dim3(4 * (NV / NB)), dim3(512), 0, stream,
                       conn_idx, conn_w, W2, hb, out, parts);
    hipLaunchKernelGGL(norm_kernel, dim3(NV / 32), dim3(256), 0, stream,
                       out, parts, bg);
}

// Round 5
// 162.117 us; speedup vs baseline: 1.0389x; 1.0389x over previous
//
#include <hip/hip_runtime.h>
#include <hip/hip_fp16.h>

// Problem constants
#define NV   20000
#define KK   3
#define INF  150
#define HH   64
#define OO   128
#define PT   80
#define KTOT 5120      // 80 bins * 64 h
#define NB   160       // vertices per geo block (125 tiles x 4 ks = 500 blocks)
#define RS   72        // pch v-row stride, halves (64 + 8 pad)
#define CB   (NB * RS) // 11520 halves = 23040 B per buffer
#define XS   168       // x/W1 LDS col stride, halves (prep kernel)
#define NBIN 20        // bins per K-slice
#define NCH  10        // bins per conn chunk (LDS holds one chunk at a time)

typedef _Float16 fh8 __attribute__((ext_vector_type(8)));   // MFMA A/B frag (4 VGPRs)
typedef __attribute__((ext_vector_type(4))) float f32x4;    // MFMA C/D frag
typedef __attribute__((ext_vector_type(8))) unsigned short u16x8;

__device__ __forceinline__ unsigned short f2h(float f) {
    return __half_as_ushort(__float2half(f));
}
__device__ __forceinline__ float h2f(unsigned short u) {
    return __half2float(__ushort_as_half(u));
}
__device__ __forceinline__ _Float16 u2h(unsigned short u) {
    union { unsigned short s; _Float16 h; } c; c.s = u; return c.h;
}

// ---------------------------------------------------------------------------
// Fused prep kernel, v16: vectorized global loads (R4 — scalar f32 loads
// were ~2x instruction cost per G13; geo is reverted to v14 and the
// constant ~95us non-geo residual is attacked here + norm).
// Blocks 0..127: transpose Wg[o] -> W2 [S][o][kk] fp16 via LDS.
// Blocks 128..752: h = relu(x @ W1^T) -> fp16, 32 rows/block via MFMA.
// ---------------------------------------------------------------------------
__global__ __launch_bounds__(256) void prep_kernel(
    const float* __restrict__ Wg, const float* __restrict__ x,
    const float* __restrict__ W1, unsigned short* __restrict__ W2,
    unsigned short* __restrict__ hb) {
    __shared__ __align__(16) unsigned char smem[32256];
    const int tid = threadIdx.x;

    if (blockIdx.x < 128) {
        float* lds = (float*)smem;                 // 64*81 words
        const int o = blockIdx.x;
        const float* src = Wg + o * KTOT;
        // float4 loads: t = e*4; 4 consecutive bins of one h (80 % 4 == 0).
        for (int e = tid; e < KTOT / 4; e += 256) {
            const float4 v4 = ((const float4*)src)[e];
            const int t = e * 4;
            const int h = t / 80, bin = t - h * 80;
            lds[h * 81 + bin]     = v4.x;
            lds[h * 81 + bin + 1] = v4.y;
            lds[h * 81 + bin + 2] = v4.z;
            lds[h * 81 + bin + 3] = v4.w;
        }
        __syncthreads();
        // paired u16 -> one u32 store; t even, (t&31)<=30 so same 32-chunk.
        for (int e = tid; e < KTOT / 2; e += 256) {
            const int t = e * 2;
            const unsigned int h0 = f2h(lds[(t & 63) * 81 + (t >> 6)]);
            const unsigned int h1 = f2h(lds[((t + 1) & 63) * 81 + ((t + 1) >> 6)]);
            *(unsigned int*)(W2 + (t >> 5) * 4096 + o * 32 + (t & 31)) =
                h0 | (h1 << 16);
        }
        return;
    }

    unsigned short* xs = (unsigned short*)smem;    // 32*168
    unsigned short* ws = xs + 32 * XS;             // 64*168
    const int n0 = (blockIdx.x - 128) * 32;

    // x rows: 32*150 f32 = 2400 float2 (150 even -> no row straddle).
    {
        const float2* x2 = (const float2*)(x + (size_t)n0 * INF);
        for (int e = tid; e < 32 * (INF / 2); e += 256) {
            const int f = e * 2;
            const int r = f / INF, c = f - r * INF;   // c even
            const float2 v = x2[e];
            const unsigned int p =
                (unsigned int)f2h(v.x) | ((unsigned int)f2h(v.y) << 16);
            *(unsigned int*)(xs + r * XS + c) = p;
        }
    }
    // zero-fill x pad: 18 cols = 9 u32 per row.
    for (int e = tid; e < 32 * 9; e += 256) {
        const int r = e / 9, c2 = e - r * 9;
        *(unsigned int*)(xs + r * XS + 150 + c2 * 2) = 0;
    }
    // W1: 64*150 f32 = 4800 float2.
    {
        const float2* w2p = (const float2*)W1;
        for (int e = tid; e < 64 * (INF / 2); e += 256) {
            const int f = e * 2;
            const int r = f / INF, c = f - r * INF;
            const float2 v = w2p[e];
            const unsigned int p =
                (unsigned int)f2h(v.x) | ((unsigned int)f2h(v.y) << 16);
            *(unsigned int*)(ws + r * XS + c) = p;
        }
    }
    for (int e = tid; e < 64 * 9; e += 256) {
        const int r = e / 9, c2 = e - r * 9;
        *(unsigned int*)(ws + r * XS + 150 + c2 * 2) = 0;
    }
    __syncthreads();

    const int wv   = tid >> 6;
    const int lane = tid & 63;
    const int q    = lane >> 4;
    const int r16  = lane & 15;
    const int o0   = wv * 16;

    f32x4 acc0 = {0.f, 0.f, 0.f, 0.f};
    f32x4 acc1 = acc0;
    #pragma unroll
    for (int s = 0; s < 5; s++) {
        const int kb = s * 32 + q * 8;
        fh8 a0 = *(const fh8*)(xs + r16 * XS + kb);
        fh8 a1 = *(const fh8*)(xs + (16 + r16) * XS + kb);
        fh8 b  = *(const fh8*)(ws + (o0 + r16) * XS + kb);
        acc0 = __builtin_amdgcn_mfma_f32_16x16x32_f16(a0, b, acc0, 0, 0, 0);
        acc1 = __builtin_amdgcn_mfma_f32_16x16x32_f16(a1, b, acc1, 0, 0, 0);
    }
    #pragma unroll
    for (int r = 0; r < 4; r++) {
        float v0 = acc0[r] > 0.f ? acc0[r] : 0.f;
        float v1 = acc1[r] > 0.f ? acc1[r] : 0.f;
        hb[(n0 + q * 4 + r) * HH + o0 + r16]      = f2h(v0);
        hb[(n0 + 16 + q * 4 + r) * HH + o0 + r16] = f2h(v1);
    }
}

// ---------------------------------------------------------------------------
// Geo kernel v14 (EXACT revert -- best measured: 63us).
// R4 post-mortem: v15's 2m x 4o grid halved LDS conflicts exactly as
// predicted (6.4M->3.2M) but added +28 MB HBM (FETCH 47.5->60.5, WRITE
// 32.8->48) and regressed 63->73.5us. LDS was NOT the binding pipe;
// keep v14's 8-wave pure-o-split which empirically has the best L2/write
// behavior. Single-round grid: 125 tiles x 4 ks = 500 blocks <= 512
// capacity. Conn staged in two 10-bin chunks (chunk1 parked in regs,
// drained at bin 9 behind a barrier).
// Deterministic partials: ks=0 -> fp32 d_out, ks>=1 -> fp16 parts[ks-1].
// ---------------------------------------------------------------------------
__global__ __launch_bounds__(512, 4) void geo_kernel(
    const int*   __restrict__ conn_idx, const float* __restrict__ conn_w,
    const unsigned short* __restrict__ W2, const unsigned short* __restrict__ hb,
    float* __restrict__ out, unsigned short* __restrict__ parts) {
    __shared__ __align__(16) unsigned short pch[2 * CB];       // 46080 B
    __shared__ __align__(16) unsigned short cp[NB * NCH * 8];  // 25600 B packed conn

    const int tid  = threadIdx.x;
    const int ks   = blockIdx.x & 3;             // K-slice 0..3
    const int n0   = (blockIdx.x >> 2) * NB;     // 0..124 * 160
    const int wv   = tid >> 6;                   // wave 0..7 = o-frag
    const int lane = tid & 63;
    const int q    = lane >> 4;
    const int r16  = lane & 15;
    const int j8   = tid & 7;                    // 16B segment of h row
    const int v0   = tid >> 3;                   // vertex 0..63 (also +64, +128)
    const bool lo  = (tid < 256);                // waves 0..3 own rows 128..159
    const int bbase = ks * NBIN;
    const int Sbase = ks * 40;                   // first 32-k step

    // Chunk 0 conn -> LDS, packed: cp[(v*NCH+cc)*8] = [i0,i1,i2,w0,w1,w2,0,0]
    for (int e = tid; e < NB * NCH; e += 512) {
        const int v = e / NCH, cc = e - v * NCH;
        const int g = (n0 + v) * (PT * KK) + (bbase + cc) * KK;
        u16x8 pk;
        pk[0] = (unsigned short)conn_idx[g];
        pk[1] = (unsigned short)conn_idx[g + 1];
        pk[2] = (unsigned short)conn_idx[g + 2];
        pk[3] = f2h(conn_w[g]);
        pk[4] = f2h(conn_w[g + 1]);
        pk[5] = f2h(conn_w[g + 2]);
        pk[6] = 0; pk[7] = 0;
        *(u16x8*)(cp + e * 8) = pk;
    }

    // Chunk 1 conn -> registers now (global latency amortized over bins 0..8),
    // drained to LDS at bin NCH-1. 1600 entries / 512 thr = 3 full + tid<64.
    u16x8 cpre0, cpre1, cpre2, cpre3 = {0, 0, 0, 0, 0, 0, 0, 0};
    {
        auto packc = [&](int e) {
            const int v = e / NCH, cc = e - v * NCH;
            const int g = (n0 + v) * (PT * KK) + (bbase + NCH + cc) * KK;
            u16x8 pk;
            pk[0] = (unsigned short)conn_idx[g];
            pk[1] = (unsigned short)conn_idx[g + 1];
            pk[2] = (unsigned short)conn_idx[g + 2];
            pk[3] = f2h(conn_w[g]);
            pk[4] = f2h(conn_w[g + 1]);
            pk[5] = f2h(conn_w[g + 2]);
            pk[6] = 0; pk[7] = 0;
            return pk;
        };
        cpre0 = packc(tid);
        cpre1 = packc(tid + 512);
        cpre2 = packc(tid + 1024);
        if (tid < NB * NCH - 1536) cpre3 = packc(tid + 1536);
    }

    f32x4 acc[10];
    #pragma unroll
    for (int m = 0; m < 10; m++) acc[m] = (f32x4){0.f, 0.f, 0.f, 0.f};

    u16x8 pa, pb, pc;    // packed conn for rows v0, v0+64, v0+128
    fh8   hva0, hva1, hva2, hvb0, hvb1, hvb2, hvc0, hvc1, hvc2;

    auto loadg = [&](int cc) {                   // conn b128 + 6..9 gathers
        const int bb = (cc >= NCH) ? cc - NCH : cc;
        pa = *(const u16x8*)(cp + (v0 * NCH + bb) * 8);
        pb = *(const u16x8*)(cp + ((v0 + 64) * NCH + bb) * 8);
        hva0 = *(const fh8*)(hb + (int)pa[0] * HH + j8 * 8);
        hva1 = *(const fh8*)(hb + (int)pa[1] * HH + j8 * 8);
        hva2 = *(const fh8*)(hb + (int)pa[2] * HH + j8 * 8);
        hvb0 = *(const fh8*)(hb + (int)pb[0] * HH + j8 * 8);
        hvb1 = *(const fh8*)(hb + (int)pb[1] * HH + j8 * 8);
        hvb2 = *(const fh8*)(hb + (int)pb[2] * HH + j8 * 8);
        if (lo) {                                // wave-uniform (waves 0..3)
            pc = *(const u16x8*)(cp + ((v0 + 128) * NCH + bb) * 8);
            hvc0 = *(const fh8*)(hb + (int)pc[0] * HH + j8 * 8);
            hvc1 = *(const fh8*)(hb + (int)pc[1] * HH + j8 * 8);
            hvc2 = *(const fh8*)(hb + (int)pc[2] * HH + j8 * 8);
        }
    };
    auto cwr = [&](unsigned short* buf) {        // combine + 2..3 LDS b128 writes
        const _Float16 a0 = u2h(pa[3]), a1 = u2h(pa[4]), a2 = u2h(pa[5]);
        const _Float16 b0 = u2h(pb[3]), b1 = u2h(pb[4]), b2 = u2h(pb[5]);
        const fh8 A0 = {a0, a0, a0, a0, a0, a0, a0, a0};
        const fh8 A1 = {a1, a1, a1, a1, a1, a1, a1, a1};
        const fh8 A2 = {a2, a2, a2, a2, a2, a2, a2, a2};
        const fh8 B0 = {b0, b0, b0, b0, b0, b0, b0, b0};
        const fh8 B1 = {b1, b1, b1, b1, b1, b1, b1, b1};
        const fh8 B2 = {b2, b2, b2, b2, b2, b2, b2, b2};
        fh8 ra = hva0 * A0 + hva1 * A1 + hva2 * A2;
        fh8 rb = hvb0 * B0 + hvb1 * B1 + hvb2 * B2;
        *(fh8*)(buf + v0 * RS + j8 * 8)        = ra;
        *(fh8*)(buf + (v0 + 64) * RS + j8 * 8) = rb;
        if (lo) {
            const _Float16 c0 = u2h(pc[3]), c1 = u2h(pc[4]), c2 = u2h(pc[5]);
            const fh8 C0 = {c0, c0, c0, c0, c0, c0, c0, c0};
            const fh8 C1 = {c1, c1, c1, c1, c1, c1, c1, c1};
            const fh8 C2 = {c2, c2, c2, c2, c2, c2, c2, c2};
            fh8 rc = hvc0 * C0 + hvc1 * C1 + hvc2 * C2;
            *(fh8*)(buf + (v0 + 128) * RS + j8 * 8) = rc;
        }
    };
    auto mfmaph = [&](const unsigned short* buf, int cc) {   // 20 MFMA
        const unsigned short* wp =
            W2 + (Sbase + cc * 2) * 4096 + (wv * 16 + r16) * 32 + q * 8;
        const fh8 bf0 = *(const fh8*)(wp);           // hoisted: both W2 frags
        const fh8 bf1 = *(const fh8*)(wp + 4096);    //   issue before ds_reads
        #pragma unroll
        for (int s = 0; s < 2; s++) {
            const int ao = s * 32 + q * 8;
            const fh8 bf = s ? bf1 : bf0;
            #pragma unroll
            for (int m = 0; m < 10; m++) {
                fh8 af = *(const fh8*)(buf + (m * 16 + r16) * RS + ao);
                acc[m] = __builtin_amdgcn_mfma_f32_16x16x32_f16(af, bf, acc[m], 0, 0, 0);
            }
        }
    };

    __syncthreads();                             // cp chunk0 visible

    // Prologue: bin 0 staged into buffer 0
    loadg(0);
    cwr(pch);
    __syncthreads();

    #pragma unroll 1
    for (int cc = 0; cc < NBIN; cc++) {
        if (cc == NCH - 1) {
            // Drain chunk1 regs -> cp. Prior barrier (end of bin NCH-2)
            // guarantees every wave finished loadg(NCH-1) reads of chunk0.
            *(u16x8*)(cp + tid * 8)          = cpre0;
            *(u16x8*)(cp + (tid + 512) * 8)  = cpre1;
            *(u16x8*)(cp + (tid + 1024) * 8) = cpre2;
            if (tid < NB * NCH - 1536)
                *(u16x8*)(cp + (tid + 1536) * 8) = cpre3;
            __syncthreads();
        }
        if (cc + 1 < NBIN) loadg(cc + 1);        // gathers in flight over MFMA
        mfmaph(&pch[(cc & 1) * CB], cc);
        if (cc + 1 < NBIN) cwr(&pch[((cc + 1) & 1) * CB]);
        __syncthreads();
    }

    // Partial store. D layout: row = q*4+reg, col = r16. 125*160 = 20000
    // exactly -> no guards. One writer per element per stage.
    if (ks == 0) {
        #pragma unroll
        for (int m = 0; m < 10; m++) {
            const int rb = n0 + m * 16 + q * 4;
            #pragma unroll
            for (int r = 0; r < 4; r++)
                out[(rb + r) * OO + wv * 16 + r16] = acc[m][r];
        }
    } else {
        unsigned short* pp = parts + (ks - 1) * (NV * OO);
        #pragma unroll
        for (int m = 0; m < 10; m++) {
            const int rb = n0 + m * 16 + q * 4;
            #pragma unroll
            for (int r = 0; r < 4; r++)
                pp[(rb + r) * OO + wv * 16 + r16] = f2h(acc[m][r]);
        }
    }
}

// ---------------------------------------------------------------------------
// Epilogue v16: vectorized. 32 rows/block, 8 threads/row; lane l owns cols
// [l*16, l*16+16). Loads: 4 float4 (out) + 6 u16x8 (parts) + 4 float4 (bg)
// = 14 instrs vs 64 scalar. Reads then fully overwrites d_out.
// ---------------------------------------------------------------------------
__global__ __launch_bounds__(256) void norm_kernel(
    float* __restrict__ out, const unsigned short* __restrict__ parts,
    const float* __restrict__ bg) {
    const int tid  = threadIdx.x;
    const int n    = blockIdx.x * 32 + (tid >> 3);
    const int l    = tid & 7;
    const int base = n * OO + l * 16;            // 16-float col slice

    float4 o4[4];
    #pragma unroll
    for (int i = 0; i < 4; i++)
        o4[i] = *(const float4*)(out + base + i * 4);

    u16x8 p[3][2];
    #pragma unroll
    for (int s = 0; s < 3; s++) {
        p[s][0] = *(const u16x8*)(parts + s * (NV * OO) + base);
        p[s][1] = *(const u16x8*)(parts + s * (NV * OO) + base + 8);
    }

    float4 b4[4];
    #pragma unroll
    for (int i = 0; i < 4; i++)
        b4[i] = *(const float4*)(bg + l * 16 + i * 4);

    float v[16];
    float s = 0.f;
    #pragma unroll
    for (int i = 0; i < 16; i++) {
        const float ov = (i & 3) == 0 ? o4[i >> 2].x :
                         (i & 3) == 1 ? o4[i >> 2].y :
                         (i & 3) == 2 ? o4[i >> 2].z : o4[i >> 2].w;
        const float bv = (i & 3) == 0 ? b4[i >> 2].x :
                         (i & 3) == 1 ? b4[i >> 2].y :
                         (i & 3) == 2 ? b4[i >> 2].z : b4[i >> 2].w;
        v[i] = ov + h2f(p[0][i >> 3][i & 7]) + h2f(p[1][i >> 3][i & 7]) +
               h2f(p[2][i >> 3][i & 7]) + bv;
        s += v[i] * v[i];
    }
    for (int off = 4; off; off >>= 1) s += __shfl_down(s, off, 8);
    const float r = rsqrtf(__shfl(s, 0, 8));
    #pragma unroll
    for (int i = 0; i < 4; i++) {
        float4 w = {v[i * 4] * r, v[i * 4 + 1] * r,
                    v[i * 4 + 2] * r, v[i * 4 + 3] * r};
        *(float4*)(out + base + i * 4) = w;
    }
}

// ---------------------------------------------------------------------------
extern "C" void kernel_launch(void* const* d_in, const int* in_sizes, int n_in,
                              void* d_out, int out_size, void* d_ws, size_t ws_size,
                              hipStream_t stream) {
    const float* x        = (const float*)d_in[0];
    const int*   conn_idx = (const int*)  d_in[1];
    const float* conn_w   = (const float*)d_in[2];
    const float* W1       = (const float*)d_in[3];
    const float* Wg       = (const float*)d_in[4];
    const float* bg       = (const float*)d_in[5];
    float*       out      = (float*)d_out;

    unsigned short* W2    = (unsigned short*)d_ws;         // 655,360 fp16 (1.31 MB)
    unsigned short* hb    = W2 + OO * KTOT;                // 1,280,000 fp16 (2.56 MB)
    unsigned short* parts = hb + NV * HH;                  // 3 x 2,560,000 fp16 (15.4 MB)

    hipLaunchKernelGGL(prep_kernel, dim3(128 + NV / 32), dim3(256), 0, stream,
                       Wg, x, W1, W2, hb);
    hipLaunchKernelGGL(geo_kernel, dim3(4 * (NV / NB)), dim3(512), 0, stream,
                       conn_idx, conn_w, W2, hb, out, parts);
    hipLaunchKernelGGL(norm_kernel, dim3(NV / 32), dim3(256), 0, stream,
                       out, parts, bg);
}